// Round 6
// baseline (1060.612 us; speedup 1.0000x reference)
//
#include <hip/hip_runtime.h>

typedef float v2f __attribute__((ext_vector_type(2)));
typedef float v4f __attribute__((ext_vector_type(4)));

#define N_IN   131072
#define K_EMB  1024
#define D_EMB  64
#define QUANT_OFF 1
#define PERP_OFF  (1 + N_IN * D_EMB)      /* 8388609 */
#define ENC_OFF   (PERP_OFF + 1)          /* 8388610: byte offset %16==8 -> float2 stores only */

#define AS1 __attribute__((address_space(1)))
#define AS3 __attribute__((address_space(3)))

// async global->LDS DMA, 16B per lane, LDS dest = uniform base + lane*16
__device__ __forceinline__ void gld16(const float* g, float* l) {
  __builtin_amdgcn_global_load_lds((const AS1 void*)g, (AS3 void*)l, 16, 0, 0);
}

// ws layout (4-byte units):
//   [0..1023]    counts (u32)
//   [1024]       loss accumulator (f32)
//   [2048..3071] half squared norms of codes (f32)

__global__ __launch_bounds__(256) void k_prep(const float* __restrict__ emb,
                                              float* __restrict__ ws) {
  int k = blockIdx.x * 256 + threadIdx.x;  // grid=4 -> k in [0,1024)
  ((unsigned int*)ws)[k] = 0u;
  if (k == 0) ws[1024] = 0.0f;
  const float* e = emb + (size_t)k * D_EMB;
  double s = 0.0;
  #pragma unroll
  for (int d = 0; d < D_EMB; ++d) { double v = (double)e[d]; s += v * v; }
  ws[2048 + k] = (float)(0.5 * s);
}

// Scan kernel. History:
//   R2: s_load codes, 2048 waves              -> 766 us (grid-starved)
//   R4: 4-way split, divergent code addr      -> 1083 us (per-lane vector loads)
//   R5: readfirstlane -> s_load + 8192 waves  -> 465 us, VALUBusy 37.7%
//       -> scalar-K$ miss-queue serialization suspected (SGPR pipe can't deepen)
// R6: codes stream via global_load_lds -> LDS, consumed as broadcast
// ds_read_b128 (vector path, deep pipelining). Per-wave private double
// buffer, no barriers in the K-loop. Stores split into k_write.
__global__ __launch_bounds__(256, 2) void k_scan(const float* __restrict__ xg,
                                                 const float* __restrict__ emb,
                                                 float* __restrict__ out,
                                                 float* __restrict__ ws) {
  __shared__ float cbuf[4][2][8 * 64];   // 4 waves x 2 bufs x 8 codes = 16 KB
  __shared__ float hn_sh[1024];          // 4 KB
  __shared__ float sc_sh[256];
  __shared__ int   id_sh[256];
  __shared__ float red[256];

  const int tid = threadIdx.x;
  const int s   = tid & 63;                                  // lane / sample slot
  const int wid = __builtin_amdgcn_readfirstlane(tid >> 6);  // wave = K-group
  const size_t row = (size_t)blockIdx.x * 64 + s;

  // half-norms -> LDS (cooperative)
  #pragma unroll
  for (int i = 0; i < 4; ++i) hn_sh[tid + i * 256] = ws[2048 + tid + i * 256];

  // x fully register-resident: 16 x float4
  v4f xr[16];
  const v4f* xp = (const v4f*)(xg + row * D_EMB);
  #pragma unroll
  for (int j = 0; j < 16; ++j) xr[j] = xp[j];

  const int k0 = wid << 8;               // 256 codes per wave
  float* b0 = &cbuf[wid][0][0];
  float* b1 = &cbuf[wid][1][0];

  // stage chunks 0,1 (chunk = 8 codes = 512 floats = 2 gld16 of 1 KB)
  {
    const float* g = emb + ((size_t)k0 << 6) + (s << 2);
    gld16(g,       b0); gld16(g + 256, b0 + 256);
    gld16(g + 512, b1); gld16(g + 768, b1 + 256);
  }

  __syncthreads();   // hn_sh ready (also drains vmcnt once)

  float best = 3.4e38f;
  int   bidx = k0;

  #pragma unroll 1
  for (int ch = 0; ch < 32; ++ch) {
    // wait until current chunk's 2 DMA writes landed (leave next chunk's 2 in flight)
    __builtin_amdgcn_s_waitcnt(0x0F72);  // vmcnt(2), exp/lgkm unmasked
    const v4f* cb = (const v4f*)((ch & 1) ? b1 : b0);
    const int kb = k0 + ch * 8;
    #pragma unroll
    for (int c = 0; c < 8; ++c) {
      v4f acc; acc.x = 0.f; acc.y = 0.f; acc.z = 0.f; acc.w = 0.f;
      #pragma unroll
      for (int j = 0; j < 16; ++j) {
        v4f ev = cb[c * 16 + j];         // broadcast ds_read_b128 (all lanes same addr)
        acc.x = fmaf(xr[j].x, ev.x, acc.x);
        acc.y = fmaf(xr[j].y, ev.y, acc.y);
        acc.z = fmaf(xr[j].z, ev.z, acc.z);
        acc.w = fmaf(xr[j].w, ev.w, acc.w);
      }
      float dot = (acc.x + acc.y) + (acc.z + acc.w);
      float sc  = hn_sh[kb + c] - dot;   // 0.5||e||^2 - x.e : same argmin as full dist
      bool cnd = sc < best;              // strict <: lowest k wins ties
      best = cnd ? sc : best;
      bidx = cnd ? (kb + c) : bidx;
    }
    // restage the just-consumed buffer with chunk ch+2 (wrap-masked; extras harmless)
    {
      const int nc = (ch + 2) & 31;
      float* dst = (ch & 1) ? b1 : b0;
      const float* g2 = emb + ((size_t)(k0 + nc * 8) << 6) + (s << 2);
      gld16(g2, dst); gld16(g2 + 256, dst + 256);
    }
  }

  sc_sh[tid] = best;
  id_sh[tid] = bidx;
  __syncthreads();

  // 4-way merge: ascending group order + strict < preserves argmin-first ties
  float lsum = 0.0f;
  if (tid < 64) {
    float b = sc_sh[tid];
    int   bi = id_sh[tid];
    #pragma unroll
    for (int gg = 1; gg < 4; ++gg) {
      float sg = sc_sh[tid + gg * 64];
      int   ig = id_sh[tid + gg * 64];
      if (sg < b) { b = sg; bi = ig; }
    }
    atomicAdd((unsigned int*)ws + bi, 1u);
    // stash id in the encodings row's first dword (k_write reads then overwrites)
    ((int*)(out + ENC_OFF))[(size_t)row * 1024] = bi;
    // thread tid<64 has wid==0, s==tid -> its xr IS this row's x
    const v4f* ebest = (const v4f*)(emb + ((size_t)bi << 6));
    #pragma unroll
    for (int j = 0; j < 16; ++j) {
      v4f ev = ebest[j];
      float dx;
      dx = ev.x - xr[j].x; lsum = fmaf(dx, dx, lsum);
      dx = ev.y - xr[j].y; lsum = fmaf(dx, dx, lsum);
      dx = ev.z - xr[j].z; lsum = fmaf(dx, dx, lsum);
      dx = ev.w - xr[j].w; lsum = fmaf(dx, dx, lsum);
    }
  }
  red[tid] = lsum;
  __syncthreads();
  #pragma unroll
  for (int off = 128; off > 0; off >>= 1) {
    if (tid < off) red[tid] += red[tid + off];
    __syncthreads();
  }
  if (tid == 0) atomicAdd(ws + 1024, red[0]);
}

// Pure-bandwidth store kernel: quantized (134 MB) + one-hot encodings (512 MB).
__global__ __launch_bounds__(256, 2) void k_write(const float* __restrict__ xg,
                                                  const float* __restrict__ emb,
                                                  float* __restrict__ out) {
  __shared__ int ids[64];
  const int tid = threadIdx.x;
  const size_t r0 = (size_t)blockIdx.x * 64;

  if (tid < 64) ids[tid] = ((const int*)(out + ENC_OFF))[(r0 + tid) * 1024];
  __syncthreads();

  // quantized = x + (e - x), scalar dword stores (QUANT_OFF=1 breaks alignment)
  float* qblk = out + QUANT_OFF + r0 * 64;
  const float* xblk = xg + r0 * 64;
  #pragma unroll 1
  for (int it = 0; it < 16; ++it) {
    int f = it * 256 + tid;
    int r = f >> 6, d = f & 63;
    float ev = emb[((size_t)ids[r] << 6) + d];
    float xv = xblk[f];
    __builtin_nontemporal_store(xv + (ev - xv), qblk + f);
  }

  // encodings: 64 rows x 1024 one-hot, v2f stores (base byte offset %16==8)
  v2f* eblk = (v2f*)(out + ENC_OFF) + r0 * 512;
  #pragma unroll 1
  for (int r = 0; r < 64; ++r) {
    int hit = ids[r];
    int hc  = hit >> 1;
    v2f one; one.x = (hit & 1) ? 0.0f : 1.0f; one.y = (hit & 1) ? 1.0f : 0.0f;
    v2f zer; zer.x = 0.0f; zer.y = 0.0f;
    v2f* rowp = eblk + (size_t)r * 512;
    __builtin_nontemporal_store((hc == tid)       ? one : zer, rowp + tid);
    __builtin_nontemporal_store((hc == tid + 256) ? one : zer, rowp + tid + 256);
  }
}

__global__ __launch_bounds__(256) void k_fin(float* __restrict__ out,
                                             const float* __restrict__ ws) {
  __shared__ float red[256];
  const unsigned int* counts = (const unsigned int*)ws;
  int t = threadIdx.x;
  float s = 0.0f;
  #pragma unroll
  for (int i = 0; i < 4; ++i) {
    float p = (float)counts[t + i * 256] * (1.0f / (float)N_IN);
    s += p * __logf(p + 1e-10f);
  }
  red[t] = s;
  __syncthreads();
  #pragma unroll
  for (int off = 128; off > 0; off >>= 1) {
    if (t < off) red[t] += red[t + off];
    __syncthreads();
  }
  if (t == 0) {
    out[PERP_OFF] = __expf(-red[0]);
    out[0] = 0.25f * ws[1024] * (1.0f / (float)(N_IN * D_EMB));
  }
}

extern "C" void kernel_launch(void* const* d_in, const int* in_sizes, int n_in,
                              void* d_out, int out_size, void* d_ws, size_t ws_size,
                              hipStream_t stream) {
  (void)in_sizes; (void)n_in; (void)out_size; (void)ws_size;
  const float* x   = (const float*)d_in[0];
  const float* emb = (const float*)d_in[1];
  float* out = (float*)d_out;
  float* ws  = (float*)d_ws;

  hipLaunchKernelGGL(k_prep,  dim3(4),    dim3(256), 0, stream, emb, ws);
  hipLaunchKernelGGL(k_scan,  dim3(2048), dim3(256), 0, stream, x, emb, out, ws);
  hipLaunchKernelGGL(k_write, dim3(2048), dim3(256), 0, stream, x, emb, out);
  hipLaunchKernelGGL(k_fin,   dim3(1),    dim3(256), 0, stream, out, ws);
}

// Round 7
// 771.812 us; speedup vs baseline: 1.3742x; 1.3742x over previous
//
#include <hip/hip_runtime.h>

typedef float v2f __attribute__((ext_vector_type(2)));
typedef float v4f __attribute__((ext_vector_type(4)));

#define N_IN   131072
#define K_EMB  1024
#define D_EMB  64
#define QUANT_OFF 1
#define PERP_OFF  (1 + N_IN * D_EMB)      /* 8388609 */
#define ENC_OFF   (PERP_OFF + 1)          /* 8388610: byte offset %16==8 -> float2 stores only */

// ws layout (4-byte units):
//   [0..1023]    counts (u32)
//   [1024]       loss accumulator (f32)
//   [2048..3071] half squared norms of codes (f32)

__global__ __launch_bounds__(256) void k_prep(const float* __restrict__ emb,
                                              float* __restrict__ ws) {
  int k = blockIdx.x * 256 + threadIdx.x;  // grid=4 -> k in [0,1024)
  ((unsigned int*)ws)[k] = 0u;
  if (k == 0) ws[1024] = 0.0f;
  const float* e = emb + (size_t)k * D_EMB;
  double s = 0.0;
  #pragma unroll
  for (int d = 0; d < D_EMB; ++d) { double v = (double)e[d]; s += v * v; }
  ws[2048 + k] = (float)(0.5 * s);
}

// R7: register-tiled fp32 GEMM scan. History of operand-supply failures:
//   R5 s_load/SGPR: can't double-buffer in ~102 SGPRs -> 290us stall (465us)
//   R6 LDS broadcast: 16 ds_read per 64 FMA-pairs -> dependent-chain bound (470us)
// Fix: outer product. Thread = 8 samples x 8 codes; per k-step 4 ds_read_b128
// feed 64 FMAs (8 FMA per b128 instead of 1). 128x128 tile, 8 N-tiles.
// E-tile stored as two half-fragments (stride-4-float across tx -> 2-way bank
// aliasing, free). Loss/quantized/one-hot stores fused (R6: fission un-hides them).
__global__ __launch_bounds__(256, 2) void k_gemm(const float* __restrict__ xg,
                                                 const float* __restrict__ emb,
                                                 float* __restrict__ out,
                                                 float* __restrict__ ws) {
  __shared__ float Xs[64 * 128];                       // 32 KB: Xs[k][m]
  __shared__ union {
    struct { v4f A[64 * 16]; v4f B[64 * 16]; } es;     // 32 KB: A[k][q]=codes q*8+0..3 dim k
    struct { float sc[2048]; int id[2048]; } red;      // 16 KB argmin-reduce scratch
  } U;
  __shared__ float hn_sh[1024];                        // 4 KB
  __shared__ int   ids[128];
  __shared__ float lred[256];

  const int t  = threadIdx.x;
  const int tx = t & 15;          // code-fragment column (8 codes)
  const int ty = t >> 4;          // sample-fragment row (8 samples)
  const size_t m0 = (size_t)blockIdx.x * 128;

  // half-norms -> LDS
  #pragma unroll
  for (int i = 0; i < 4; ++i) hn_sh[t + i * 256] = ws[2048 + t + i * 256];

  // stage X[128][64] -> Xs[k][m] (transposed, k-major)
  {
    const v4f* xp4 = (const v4f*)(xg + m0 * 64);
    #pragma unroll
    for (int i = 0; i < 8; ++i) {
      int f4 = t + i * 256;              // 2048 float4s
      int m = f4 >> 4, dq = (f4 & 15) * 4;
      v4f v = xp4[f4];
      Xs[(dq + 0) * 128 + m] = v.x;
      Xs[(dq + 1) * 128 + m] = v.y;
      Xs[(dq + 2) * 128 + m] = v.z;
      Xs[(dq + 3) * 128 + m] = v.w;
    }
  }
  __syncthreads();

  float best[8];
  int   bidx[8];
  #pragma unroll
  for (int i = 0; i < 8; ++i) { best[i] = 3.4e38f; bidx[i] = 0; }

  #pragma unroll 1
  for (int nt = 0; nt < 8; ++nt) {
    // stage E-tile [nt*128,+128) -> split fragments A/B
    {
      const v4f* ep4 = (const v4f*)(emb + (size_t)nt * 128 * 64);
      #pragma unroll
      for (int i = 0; i < 8; ++i) {
        int f4 = t + i * 256;
        int n = f4 >> 4, dq = (f4 & 15) * 4;
        v4f v = ep4[f4];
        int q = n >> 3, cc = n & 3;
        float* dst = ((n & 7) < 4) ? (float*)U.es.A : (float*)U.es.B;
        dst[((dq + 0) * 16 + q) * 4 + cc] = v.x;
        dst[((dq + 1) * 16 + q) * 4 + cc] = v.y;
        dst[((dq + 2) * 16 + q) * 4 + cc] = v.z;
        dst[((dq + 3) * 16 + q) * 4 + cc] = v.w;
      }
    }
    __syncthreads();

    float acc[8][8];
    #pragma unroll
    for (int i = 0; i < 8; ++i)
      #pragma unroll
      for (int j = 0; j < 8; ++j) acc[i][j] = 0.f;

    #pragma unroll 4
    for (int k = 0; k < 64; ++k) {
      v4f a0 = *(const v4f*)&Xs[k * 128 + ty * 8];       // broadcast (4 addrs/wave)
      v4f a1 = *(const v4f*)&Xs[k * 128 + ty * 8 + 4];
      v4f b0 = U.es.A[k * 16 + tx];                      // 2-way bank alias: free
      v4f b1 = U.es.B[k * 16 + tx];
      float a[8] = {a0.x, a0.y, a0.z, a0.w, a1.x, a1.y, a1.z, a1.w};
      float b[8] = {b0.x, b0.y, b0.z, b0.w, b1.x, b1.y, b1.z, b1.w};
      #pragma unroll
      for (int i = 0; i < 8; ++i)
        #pragma unroll
        for (int j = 0; j < 8; ++j)
          acc[i][j] = fmaf(a[i], b[j], acc[i][j]);       // k ascending: matches ref order
    }

    // fold this N-tile into the running argmin (j ascending = code ascending)
    #pragma unroll
    for (int j = 0; j < 8; ++j) {
      int n = nt * 128 + tx * 8 + j;
      float h = hn_sh[n];
      #pragma unroll
      for (int i = 0; i < 8; ++i) {
        float sc = h - acc[i][j];        // 0.5||e||^2 - x.e : same argmin as full dist
        bool c = sc < best[i];           // strict <: lowest code index wins ties
        best[i] = c ? sc : best[i];
        bidx[i] = c ? n : bidx[i];
      }
    }
    __syncthreads();   // Es consumed; safe to restage (or overlay red after loop)
  }

  // cross-tx argmin reduce (ascending tx preserves first-min tie rule)
  #pragma unroll
  for (int i = 0; i < 8; ++i) {
    U.red.sc[t * 8 + i] = best[i];
    U.red.id[t * 8 + i] = bidx[i];
  }
  __syncthreads();

  if (t < 128) {
    int ty_r = t >> 3, i = t & 7;        // row r = t
    float b = 3.4e38f;
    int   bi = 0;
    #pragma unroll
    for (int xx = 0; xx < 16; ++xx) {
      float sg = U.red.sc[((ty_r * 16 + xx) * 8) + i];
      int   ig = U.red.id[((ty_r * 16 + xx) * 8) + i];
      if (sg < b) { b = sg; bi = ig; }
    }
    ids[t] = bi;
    atomicAdd((unsigned int*)ws + bi, 1u);
  }
  __syncthreads();

  // ---- fused store phase: quantized + commitment loss ----
  float lsum = 0.0f;
  {
    float* qblk = out + QUANT_OFF + m0 * 64;
    const float* xblk = xg + m0 * 64;
    #pragma unroll 1
    for (int it = 0; it < 32; ++it) {
      int f = it * 256 + t;
      int r = f >> 6, d = f & 63;
      float ev = emb[((size_t)ids[r] << 6) + d];
      float xv = xblk[f];
      float dx = ev - xv;
      lsum = fmaf(dx, dx, lsum);
      __builtin_nontemporal_store(xv + dx, qblk + f);   // x + (e-x): ref order
    }
  }
  lred[t] = lsum;
  __syncthreads();
  #pragma unroll
  for (int off = 128; off > 0; off >>= 1) {
    if (t < off) lred[t] += lred[t + off];
    __syncthreads();
  }
  if (t == 0) atomicAdd(ws + 1024, lred[0]);

  // ---- one-hot encodings (128 rows x 1024) ----
  v2f* eblk = (v2f*)(out + ENC_OFF) + m0 * 512;
  #pragma unroll 1
  for (int r = 0; r < 128; ++r) {
    int hit = ids[r];                    // broadcast LDS read
    int hc  = hit >> 1;
    v2f one; one.x = (hit & 1) ? 0.0f : 1.0f; one.y = (hit & 1) ? 1.0f : 0.0f;
    v2f zer; zer.x = 0.0f; zer.y = 0.0f;
    v2f* rowp = eblk + (size_t)r * 512;
    __builtin_nontemporal_store((hc == t)       ? one : zer, rowp + t);
    __builtin_nontemporal_store((hc == t + 256) ? one : zer, rowp + t + 256);
  }
}

__global__ __launch_bounds__(256) void k_fin(float* __restrict__ out,
                                             const float* __restrict__ ws) {
  __shared__ float red[256];
  const unsigned int* counts = (const unsigned int*)ws;
  int t = threadIdx.x;
  float s = 0.0f;
  #pragma unroll
  for (int i = 0; i < 4; ++i) {
    float p = (float)counts[t + i * 256] * (1.0f / (float)N_IN);
    s += p * __logf(p + 1e-10f);
  }
  red[t] = s;
  __syncthreads();
  #pragma unroll
  for (int off = 128; off > 0; off >>= 1) {
    if (t < off) red[t] += red[t + off];
    __syncthreads();
  }
  if (t == 0) {
    out[PERP_OFF] = __expf(-red[0]);
    out[0] = 0.25f * ws[1024] * (1.0f / (float)(N_IN * D_EMB));
  }
}

extern "C" void kernel_launch(void* const* d_in, const int* in_sizes, int n_in,
                              void* d_out, int out_size, void* d_ws, size_t ws_size,
                              hipStream_t stream) {
  (void)in_sizes; (void)n_in; (void)out_size; (void)ws_size;
  const float* x   = (const float*)d_in[0];
  const float* emb = (const float*)d_in[1];
  float* out = (float*)d_out;
  float* ws  = (float*)d_ws;

  hipLaunchKernelGGL(k_prep, dim3(4),    dim3(256), 0, stream, emb, ws);
  hipLaunchKernelGGL(k_gemm, dim3(1024), dim3(256), 0, stream, x, emb, out, ws);
  hipLaunchKernelGGL(k_fin,  dim3(1),    dim3(256), 0, stream, out, ws);
}

// Round 8
// 733.685 us; speedup vs baseline: 1.4456x; 1.0520x over previous
//
#include <hip/hip_runtime.h>

typedef float v2f __attribute__((ext_vector_type(2)));
typedef float v4f __attribute__((ext_vector_type(4)));

#define N_IN   131072
#define K_EMB  1024
#define D_EMB  64
#define QUANT_OFF 1
#define PERP_OFF  (1 + N_IN * D_EMB)      /* 8388609 */
#define ENC_OFF   (PERP_OFF + 1)          /* 8388610: byte offset %16==8 -> float2 stores only */

// ws layout (4-byte units):
//   [0..1023]    counts (u32)
//   [1024]       loss accumulator (f32)
//   [2048..3071] half squared norms of codes (f32)

__global__ __launch_bounds__(256) void k_prep(const float* __restrict__ emb,
                                              float* __restrict__ ws) {
  int k = blockIdx.x * 256 + threadIdx.x;  // grid=4 -> k in [0,1024)
  ((unsigned int*)ws)[k] = 0u;
  if (k == 0) ws[1024] = 0.0f;
  const float* e = emb + (size_t)k * D_EMB;
  double s = 0.0;
  #pragma unroll
  for (int d = 0; d < D_EMB; ++d) { double v = (double)e[d]; s += v * v; }
  ws[2048 + k] = (float)(0.5 * s);
}

// R8: R7's register-tiled GEMM with the LDS-pipe fixes.
// R7 post-mortem: LDS-bound at ~360us; staging wrote with m=f4>>4 nearly
// wave-uniform -> bank=m%32 spanned only 4 banks -> 16-way conflicts on
// 64 ds_write_b32/thread (~1/3 of the kernel). Fixes:
//   (a) staging reindex f4=8t+i -> write bank=(t>>1)%32 -> 2-way (free);
//       global side: each lane's 8 v4f are 128B-contiguous (L1 absorbs).
//   (b) E-fragment arrays padded 16->17 v4f/row -> b-reads/writes <=2-way.
//   (c) next E-tile prefetched into registers during the k-loop -> the
//       barrier fences only a short LDS burst, not a global round-trip.
// Per-score FMA order unchanged -> bit-identical outputs.
__global__ __launch_bounds__(256, 2) void k_gemm(const float* __restrict__ xg,
                                                 const float* __restrict__ emb,
                                                 float* __restrict__ out,
                                                 float* __restrict__ ws) {
  __shared__ float Xs[64 * 128];                         // 32 KB: Xs[k][m]
  __shared__ union {
    struct { v4f A[64 * 17 + 1]; v4f B[64 * 17]; } es;   // 34.8 KB padded frags
    struct { float sc[2048]; int id[2048]; } red;        // 16 KB argmin scratch
  } U;
  __shared__ float hn_sh[1024];                          // 4 KB
  __shared__ int   ids[128];
  __shared__ float lred[256];

  const int t  = threadIdx.x;
  const int tx = t & 15;          // code-fragment column (8 codes)
  const int ty = t >> 4;          // sample-fragment row (8 samples)
  const size_t m0 = (size_t)blockIdx.x * 128;

  // staging geometry for f4 = 8t+i: n/m = t>>1, dq = (8(t&1)+i)*4
  const int colh = t >> 1;              // column (code or sample) this thread fills
  const int dqb  = (t & 1) * 32;        // dim base: even threads dims 0..31, odd 32..63
  const int qE   = t >> 4;              // E-fragment q
  const int ccE  = (t >> 1) & 3;        // E-fragment component
  float* frag = ((t >> 3) & 1) ? (float*)U.es.B : (float*)U.es.A;

  // half-norms -> LDS
  #pragma unroll
  for (int i = 0; i < 4; ++i) hn_sh[t + i * 256] = ws[2048 + t + i * 256];

  // prefetch E-tile 0 into registers (latency hides under Xs staging)
  v4f pf[8];
  {
    const v4f* ep4 = (const v4f*)emb;
    #pragma unroll
    for (int i = 0; i < 8; ++i) pf[i] = ep4[8 * t + i];
  }

  // stage X[128][64] -> Xs[k][m]; writes are 2-way-bank (free)
  {
    const v4f* xp4 = (const v4f*)(xg + m0 * 64);
    #pragma unroll
    for (int i = 0; i < 8; ++i) {
      v4f v = xp4[8 * t + i];
      int r0 = dqb + 4 * i;
      Xs[(r0 + 0) * 128 + colh] = v.x;
      Xs[(r0 + 1) * 128 + colh] = v.y;
      Xs[(r0 + 2) * 128 + colh] = v.z;
      Xs[(r0 + 3) * 128 + colh] = v.w;
    }
  }

  // write prefetched tile 0 into fragments (compiler waits vmcnt as needed)
  #pragma unroll
  for (int i = 0; i < 8; ++i) {
    v4f v = pf[i];
    int r0 = dqb + 4 * i;
    frag[((r0 + 0) * 17 + qE) * 4 + ccE] = v.x;
    frag[((r0 + 1) * 17 + qE) * 4 + ccE] = v.y;
    frag[((r0 + 2) * 17 + qE) * 4 + ccE] = v.z;
    frag[((r0 + 3) * 17 + qE) * 4 + ccE] = v.w;
  }
  __syncthreads();

  float best[8];
  int   bidx[8];
  #pragma unroll
  for (int i = 0; i < 8; ++i) { best[i] = 3.4e38f; bidx[i] = 0; }

  #pragma unroll 1
  for (int nt = 0; nt < 8; ++nt) {
    // issue global prefetch of tile nt+1 (registers), consumed after barrier
    if (nt < 7) {
      const v4f* ep4 = (const v4f*)(emb + (size_t)(nt + 1) * 128 * 64);
      #pragma unroll
      for (int i = 0; i < 8; ++i) pf[i] = ep4[8 * t + i];
    }

    float acc[8][8];
    #pragma unroll
    for (int i = 0; i < 8; ++i)
      #pragma unroll
      for (int j = 0; j < 8; ++j) acc[i][j] = 0.f;

    #pragma unroll 4
    for (int k = 0; k < 64; ++k) {
      v4f a0 = *(const v4f*)&Xs[k * 128 + ty * 8];       // broadcast
      v4f a1 = *(const v4f*)&Xs[k * 128 + ty * 8 + 4];
      v4f b0 = U.es.A[k * 17 + tx];                      // <=2-way
      v4f b1 = U.es.B[k * 17 + tx];
      float a[8] = {a0.x, a0.y, a0.z, a0.w, a1.x, a1.y, a1.z, a1.w};
      float b[8] = {b0.x, b0.y, b0.z, b0.w, b1.x, b1.y, b1.z, b1.w};
      #pragma unroll
      for (int i = 0; i < 8; ++i)
        #pragma unroll
        for (int j = 0; j < 8; ++j)
          acc[i][j] = fmaf(a[i], b[j], acc[i][j]);       // k ascending: ref order
    }

    // fold this N-tile into the running argmin (j ascending = code ascending)
    #pragma unroll
    for (int j = 0; j < 8; ++j) {
      int n = nt * 128 + tx * 8 + j;
      float h = hn_sh[n];
      #pragma unroll
      for (int i = 0; i < 8; ++i) {
        float sc = h - acc[i][j];        // 0.5||e||^2 - x.e : same argmin as full dist
        bool c = sc < best[i];           // strict <: lowest code index wins ties
        best[i] = c ? sc : best[i];
        bidx[i] = c ? n : bidx[i];
      }
    }
    __syncthreads();                     // everyone done reading this E-tile

    if (nt < 7) {
      #pragma unroll
      for (int i = 0; i < 8; ++i) {
        v4f v = pf[i];
        int r0 = dqb + 4 * i;
        frag[((r0 + 0) * 17 + qE) * 4 + ccE] = v.x;
        frag[((r0 + 1) * 17 + qE) * 4 + ccE] = v.y;
        frag[((r0 + 2) * 17 + qE) * 4 + ccE] = v.z;
        frag[((r0 + 3) * 17 + qE) * 4 + ccE] = v.w;
      }
    }
    __syncthreads();                     // new tile visible
  }

  // cross-tx argmin reduce (ascending tx preserves first-min tie rule)
  #pragma unroll
  for (int i = 0; i < 8; ++i) {
    U.red.sc[t * 8 + i] = best[i];
    U.red.id[t * 8 + i] = bidx[i];
  }
  __syncthreads();

  if (t < 128) {
    int ty_r = t >> 3, i = t & 7;        // row r = t
    float b = 3.4e38f;
    int   bi = 0;
    #pragma unroll
    for (int xx = 0; xx < 16; ++xx) {
      float sg = U.red.sc[((ty_r * 16 + xx) * 8) + i];
      int   ig = U.red.id[((ty_r * 16 + xx) * 8) + i];
      if (sg < b) { b = sg; bi = ig; }
    }
    ids[t] = bi;
    atomicAdd((unsigned int*)ws + bi, 1u);
  }
  __syncthreads();

  // ---- fused store phase: quantized + commitment loss ----
  float lsum = 0.0f;
  {
    float* qblk = out + QUANT_OFF + m0 * 64;
    const float* xblk = xg + m0 * 64;
    #pragma unroll 1
    for (int it = 0; it < 32; ++it) {
      int f = it * 256 + t;
      int r = f >> 6, d = f & 63;
      float ev = emb[((size_t)ids[r] << 6) + d];
      float xv = xblk[f];
      float dx = ev - xv;
      lsum = fmaf(dx, dx, lsum);
      __builtin_nontemporal_store(xv + dx, qblk + f);   // x + (e-x): ref order
    }
  }
  lred[t] = lsum;
  __syncthreads();
  #pragma unroll
  for (int off = 128; off > 0; off >>= 1) {
    if (t < off) lred[t] += lred[t + off];
    __syncthreads();
  }
  if (t == 0) atomicAdd(ws + 1024, lred[0]);

  // ---- one-hot encodings (128 rows x 1024) ----
  v2f* eblk = (v2f*)(out + ENC_OFF) + m0 * 512;
  #pragma unroll 1
  for (int r = 0; r < 128; ++r) {
    int hit = ids[r];                    // broadcast LDS read
    int hc  = hit >> 1;
    v2f one; one.x = (hit & 1) ? 0.0f : 1.0f; one.y = (hit & 1) ? 1.0f : 0.0f;
    v2f zer; zer.x = 0.0f; zer.y = 0.0f;
    v2f* rowp = eblk + (size_t)r * 512;
    __builtin_nontemporal_store((hc == t)       ? one : zer, rowp + t);
    __builtin_nontemporal_store((hc == t + 256) ? one : zer, rowp + t + 256);
  }
}

__global__ __launch_bounds__(256) void k_fin(float* __restrict__ out,
                                             const float* __restrict__ ws) {
  __shared__ float red[256];
  const unsigned int* counts = (const unsigned int*)ws;
  int t = threadIdx.x;
  float s = 0.0f;
  #pragma unroll
  for (int i = 0; i < 4; ++i) {
    float p = (float)counts[t + i * 256] * (1.0f / (float)N_IN);
    s += p * __logf(p + 1e-10f);
  }
  red[t] = s;
  __syncthreads();
  #pragma unroll
  for (int off = 128; off > 0; off >>= 1) {
    if (t < off) red[t] += red[t + off];
    __syncthreads();
  }
  if (t == 0) {
    out[PERP_OFF] = __expf(-red[0]);
    out[0] = 0.25f * ws[1024] * (1.0f / (float)(N_IN * D_EMB));
  }
}

extern "C" void kernel_launch(void* const* d_in, const int* in_sizes, int n_in,
                              void* d_out, int out_size, void* d_ws, size_t ws_size,
                              hipStream_t stream) {
  (void)in_sizes; (void)n_in; (void)out_size; (void)ws_size;
  const float* x   = (const float*)d_in[0];
  const float* emb = (const float*)d_in[1];
  float* out = (float*)d_out;
  float* ws  = (float*)d_ws;

  hipLaunchKernelGGL(k_prep, dim3(4),    dim3(256), 0, stream, emb, ws);
  hipLaunchKernelGGL(k_gemm, dim3(1024), dim3(256), 0, stream, x, emb, out, ws);
  hipLaunchKernelGGL(k_fin,  dim3(1),    dim3(256), 0, stream, out, ws);
}